// Round 1
// baseline (79.706 us; speedup 1.0000x reference)
//
#include <hip/hip_runtime.h>

// LengthRegulator: repeat encoder rows by duration, pad to t_out with zeros.
// B=32, T=512, D=512, t_out=4096 (from reference setup_inputs).

#define T_PH 512

// Kernel A: per-batch inclusive scan of max(dur,1) -> ends[b][T]
__global__ void lr_scan_kernel(const int* __restrict__ dur,
                               int* __restrict__ ends, int T) {
    __shared__ int s[T_PH];
    const int b = blockIdx.x;
    const int t = threadIdx.x;
    int v = dur[b * T + t];
    v = (v < 1) ? 1 : v;
    s[t] = v;
    __syncthreads();
    // Hillis-Steele inclusive scan over T elements
    for (int off = 1; off < T; off <<= 1) {
        int add = (t >= off) ? s[t - off] : 0;
        __syncthreads();
        s[t] += add;
        __syncthreads();
    }
    ends[b * T + t] = s[t];
}

// Kernel B: one block per output frame (b, j). Binary search ends[b] for the
// source phoneme index (searchsorted right), copy row as float4, or zero-pad.
__global__ void lr_gather_kernel(const float4* __restrict__ enc,
                                 const int* __restrict__ ends,
                                 float4* __restrict__ out,
                                 int T, int t_out, int D4) {
    const int j = blockIdx.x;   // output frame
    const int b = blockIdx.y;   // batch
    const int t = threadIdx.x;  // float4 lane within row (D4 = D/4 = 128)

    const int* __restrict__ e = ends + b * T;
    const int total = e[T - 1];

    float4 val;
    if (j < total) {
        // first idx with e[idx] > j; clamped to T-1 (guaranteed since j < total)
        int lo = 0, hi = T - 1;
        while (lo < hi) {
            int mid = (lo + hi) >> 1;
            if (e[mid] <= j) lo = mid + 1; else hi = mid;
        }
        val = enc[((size_t)b * T + lo) * D4 + t];
    } else {
        val = make_float4(0.f, 0.f, 0.f, 0.f);
    }
    out[((size_t)b * t_out + j) * D4 + t] = val;
}

extern "C" void kernel_launch(void* const* d_in, const int* in_sizes, int n_in,
                              void* d_out, int out_size, void* d_ws, size_t ws_size,
                              hipStream_t stream) {
    const float* enc = (const float*)d_in[0];
    const int* dur   = (const int*)d_in[1];
    float* out       = (float*)d_out;

    const int BT = in_sizes[1];          // B*T = 16384
    const int D  = in_sizes[0] / BT;     // 512
    const int T  = T_PH;                 // 512 (reference setup)
    const int B  = BT / T;               // 32
    const int t_out = out_size / (B * D); // 4096

    int* ends = (int*)d_ws;              // B*T ints = 64 KiB scratch

    lr_scan_kernel<<<B, T, 0, stream>>>(dur, ends, T);

    dim3 grid(t_out, B);
    lr_gather_kernel<<<grid, D / 4, 0, stream>>>(
        (const float4*)enc, ends, (float4*)out, T, t_out, D / 4);
}

// Round 3
// 58.354 us; speedup vs baseline: 1.3659x; 1.3659x over previous
//
#include <hip/hip_runtime.h>

// LengthRegulator: repeat encoder rows by duration, pad to t_out with zeros.
// B=32, T=512, D=512, t_out=4096 (from reference setup_inputs).

#define T_PH 512
#define FPB  8   // frames per block in gather kernel

typedef float f32x4 __attribute__((ext_vector_type(4)));  // native vec: ok for nontemporal builtins

// Kernel A: per-batch inclusive scan of max(dur,1) in LDS, then LDS binary
// search to produce idx[b][j] = source phoneme for output frame j (-1 = pad).
__global__ void lr_scan_idx_kernel(const int* __restrict__ dur,
                                   int* __restrict__ idx,
                                   int T, int t_out) {
    __shared__ int s[T_PH];
    const int b = blockIdx.x;
    const int t = threadIdx.x;

    int v = dur[b * T + t];
    v = (v < 1) ? 1 : v;
    s[t] = v;
    __syncthreads();
    // Hillis-Steele inclusive scan over T elements
    for (int off = 1; off < T; off <<= 1) {
        int add = (t >= off) ? s[t - off] : 0;
        __syncthreads();
        s[t] += add;
        __syncthreads();
    }
    const int total = s[T - 1];

    // Each thread computes idx for frames j = t, t+T, ... (t_out/T = 8)
    int* idxb = idx + b * t_out;
    for (int j = t; j < t_out; j += T) {
        int r;
        if (j >= total) {
            r = -1;  // zero padding
        } else {
            // first p with s[p] > j  (searchsorted right)
            int lo = 0, hi = T - 1;
            while (lo < hi) {
                int mid = (lo + hi) >> 1;
                if (s[mid] <= j) lo = mid + 1; else hi = mid;
            }
            r = lo;
        }
        idxb[j] = r;  // consecutive threads -> consecutive j: coalesced
    }
}

// Kernel B: pure bandwidth gather. Block = 256 threads handles FPB=8 frames
// (16 KiB). Thread: lane = tid&127 (f32x4 col), fh = tid>>7; 4 independent
// frame copies per thread. idx reads are wave-uniform broadcasts.
__global__ void lr_gather_kernel(const f32x4* __restrict__ enc,
                                 const int* __restrict__ idx,
                                 f32x4* __restrict__ out,
                                 int T, int t_out) {
    const int lane = threadIdx.x & 127;
    const int fh   = threadIdx.x >> 7;          // 0 or 1
    const int b    = blockIdx.y;
    const int j0   = blockIdx.x * FPB;

    const int* __restrict__ idxb = idx + b * t_out + j0;
    const f32x4* __restrict__ encb = enc + (size_t)b * T * 128;
    f32x4* __restrict__ outb = out + ((size_t)b * t_out + j0) * 128 + lane;

    const f32x4 zero = {0.f, 0.f, 0.f, 0.f};

    // Load all 4 phoneme indices first (independent), then 4 gathers, 4 stores.
    int p0 = idxb[fh + 0];
    int p1 = idxb[fh + 2];
    int p2 = idxb[fh + 4];
    int p3 = idxb[fh + 6];

    f32x4 v0 = (p0 >= 0) ? encb[(size_t)p0 * 128 + lane] : zero;
    f32x4 v1 = (p1 >= 0) ? encb[(size_t)p1 * 128 + lane] : zero;
    f32x4 v2 = (p2 >= 0) ? encb[(size_t)p2 * 128 + lane] : zero;
    f32x4 v3 = (p3 >= 0) ? encb[(size_t)p3 * 128 + lane] : zero;

    __builtin_nontemporal_store(v0, &outb[(size_t)(fh + 0) * 128]);
    __builtin_nontemporal_store(v1, &outb[(size_t)(fh + 2) * 128]);
    __builtin_nontemporal_store(v2, &outb[(size_t)(fh + 4) * 128]);
    __builtin_nontemporal_store(v3, &outb[(size_t)(fh + 6) * 128]);
}

extern "C" void kernel_launch(void* const* d_in, const int* in_sizes, int n_in,
                              void* d_out, int out_size, void* d_ws, size_t ws_size,
                              hipStream_t stream) {
    const float* enc = (const float*)d_in[0];
    const int* dur   = (const int*)d_in[1];
    float* out       = (float*)d_out;

    const int BT = in_sizes[1];           // B*T = 16384
    const int T  = T_PH;                  // 512 (reference setup)
    const int B  = BT / T;                // 32
    const int D  = in_sizes[0] / BT;      // 512 (D/4 = 128 hard-coded in kernel B)
    const int t_out = out_size / (B * D); // 4096

    int* idx = (int*)d_ws;                // B * t_out ints = 512 KiB scratch

    lr_scan_idx_kernel<<<B, T, 0, stream>>>(dur, idx, T, t_out);

    dim3 grid(t_out / FPB, B);
    lr_gather_kernel<<<grid, 256, 0, stream>>>(
        (const f32x4*)enc, idx, (f32x4*)out, T, t_out);
}

// Round 4
// 52.023 us; speedup vs baseline: 1.5321x; 1.1217x over previous
//
#include <hip/hip_runtime.h>

// LengthRegulator fused: each block recomputes the per-batch cumsum of
// max(dur,1) (2 KiB, L2-resident), binary-searches its 8 output frames,
// then does the bandwidth phase (gather enc rows / zero-pad).
// B=32, T=512, D=512, t_out=4096.

#define T_PH 512
#define FPB  8   // frames per block

typedef float f32x4 __attribute__((ext_vector_type(4)));

__global__ __launch_bounds__(256) void lr_fused_kernel(
    const f32x4* __restrict__ enc,   // [B, T, 128]
    const int*   __restrict__ dur,   // [B, T]
    f32x4*       __restrict__ out,   // [B, t_out, 128]
    int T, int t_out) {

    __shared__ int sp[T_PH / 2];   // pair-sum scan buffer (256)
    __shared__ int e[T_PH];        // ends (inclusive cumsum, 512)
    __shared__ int idx8[FPB];      // source phoneme per frame of this block

    const int tid = threadIdx.x;   // 0..255
    const int b   = blockIdx.y;
    const int j0  = blockIdx.x * FPB;

    // --- phase 1: load dur row (2 ints/thread, coalesced), pair-sum ---
    int2 d2 = ((const int2*)(dur + b * T))[tid];
    int v0 = (d2.x < 1) ? 1 : d2.x;
    int v1 = (d2.y < 1) ? 1 : d2.y;
    sp[tid] = v0 + v1;
    __syncthreads();

    // --- inclusive Hillis-Steele scan over 256 pair sums (8 steps) ---
    for (int off = 1; off < T_PH / 2; off <<= 1) {
        int add = (tid >= off) ? sp[tid - off] : 0;
        __syncthreads();
        sp[tid] += add;
        __syncthreads();
    }
    // ends: e[2t+1] = S(t), e[2t] = S(t) - v1
    int S = sp[tid];
    e[2 * tid]     = S - v1;
    e[2 * tid + 1] = S;
    __syncthreads();

    const int total = e[T_PH - 1];

    // --- phase 2: threads 0..7 binary-search their frame ---
    if (tid < FPB) {
        int j = j0 + tid;
        int r;
        if (j >= total) {
            r = -1;
        } else {
            int lo = 0, hi = T_PH - 1;
            while (lo < hi) {
                int mid = (lo + hi) >> 1;
                if (e[mid] <= j) lo = mid + 1; else hi = mid;
            }
            r = lo;
        }
        idx8[tid] = r;
    }
    __syncthreads();

    // --- phase 3: bandwidth. lane = f32x4 col, fh selects frame pairing ---
    const int lane = tid & 127;
    const int fh   = tid >> 7;  // 0 or 1

    const f32x4* __restrict__ encb = enc + (size_t)b * T_PH * 128;
    f32x4* __restrict__ outb = out + ((size_t)b * t_out + j0) * 128 + lane;

    const f32x4 zero = {0.f, 0.f, 0.f, 0.f};

    int p0 = idx8[fh + 0];
    int p1 = idx8[fh + 2];
    int p2 = idx8[fh + 4];
    int p3 = idx8[fh + 6];

    f32x4 w0 = (p0 >= 0) ? encb[(size_t)p0 * 128 + lane] : zero;
    f32x4 w1 = (p1 >= 0) ? encb[(size_t)p1 * 128 + lane] : zero;
    f32x4 w2 = (p2 >= 0) ? encb[(size_t)p2 * 128 + lane] : zero;
    f32x4 w3 = (p3 >= 0) ? encb[(size_t)p3 * 128 + lane] : zero;

    __builtin_nontemporal_store(w0, &outb[(size_t)(fh + 0) * 128]);
    __builtin_nontemporal_store(w1, &outb[(size_t)(fh + 2) * 128]);
    __builtin_nontemporal_store(w2, &outb[(size_t)(fh + 4) * 128]);
    __builtin_nontemporal_store(w3, &outb[(size_t)(fh + 6) * 128]);
}

extern "C" void kernel_launch(void* const* d_in, const int* in_sizes, int n_in,
                              void* d_out, int out_size, void* d_ws, size_t ws_size,
                              hipStream_t stream) {
    const float* enc = (const float*)d_in[0];
    const int* dur   = (const int*)d_in[1];
    float* out       = (float*)d_out;

    const int BT = in_sizes[1];           // B*T = 16384
    const int T  = T_PH;                  // 512 (reference setup)
    const int B  = BT / T;                // 32
    const int D  = in_sizes[0] / BT;      // 512 (D/4 = 128 hard-coded)
    const int t_out = out_size / (B * D); // 4096

    dim3 grid(t_out / FPB, B);
    lr_fused_kernel<<<grid, 256, 0, stream>>>(
        (const f32x4*)enc, dur, (f32x4*)out, T, t_out);
}